// Round 7
// baseline (343.760 us; speedup 1.0000x reference)
//
#include <hip/hip_runtime.h>

#define G 1024
#define SCALEF 1048576.0f         // 2^20 fixed-point for the sum (exact decode, absmax ~4e-6)
#define CNT_SHIFT 42              // block cell (u64): count [42..63], biased sum [0..41]
#define ELEM_BIAS (1 << 24)       // per-element bias (> max |vf|, |v| < 16)
#define LOW_MASK ((1ULL << CNT_SHIFT) - 1)
#define GCNT_SHIFT 44             // global cell (u64): count [44..63], biased sum below
#define GSUM_BIAS (1ll << 23)     // per-count bias (>= max per-element |vf|, |v| < 8)
#define GLOW_MASK ((1ULL << GCNT_SHIFT) - 1)
#define NREP 64                   // sum-fold replicas: 1024 blocks / 64 -> depth 16 per address
#define NREP_MM 32                // min/max replicas: depth 32 per address
#define BLK 512
#define GRID 1024

// Order-preserving map float -> uint32 (monotone): uint min/max == float min/max.
__device__ __forceinline__ unsigned omap(float x) {
    unsigned u = __float_as_uint(x);
    return (u & 0x80000000u) ? ~u : (u | 0x80000000u);
}
__device__ __forceinline__ float ounmap(unsigned o) {
    unsigned u = (o & 0x80000000u) ? (o & 0x7fffffffu) : ~o;
    return __uint_as_float(u);
}

// Single fused kernel (R7): main pass + last-block-done final reduce/write.
// Rationale: across R0-R6 the summed dispatch times are ~55us but the benched
// dur is ~160us -> ~100us of per-node launch/gap overhead. Collapse the graph
// to {memset, this kernel}. Main body = R1's proven loop (1 ds_add_u64 packed
// sum+count + 2 ungated u32 LDS min/max per element; 47.8us measured).
__global__ __launch_bounds__(BLK) void gb_fused(
    const int4* __restrict__ keys, const float4* __restrict__ vals, int n4,
    unsigned long long* __restrict__ racc,
    unsigned* __restrict__ rmaxo, unsigned* __restrict__ rminv,
    unsigned* __restrict__ done, float* __restrict__ out)
{
    __shared__ unsigned long long s_sc[G];
    __shared__ unsigned s_mn[G];
    __shared__ unsigned s_mx[G];
    for (int k = threadIdx.x; k < G; k += BLK) {
        s_sc[k] = 0ull; s_mn[k] = 0xffffffffu; s_mx[k] = 0u;
    }
    __syncthreads();

#define MAIN_ELEM(KK, VV)                                                      \
        {                                                                      \
            const int mk = (KK); const float mv = (VV);                        \
            const unsigned o = omap(mv);                                       \
            atomicMin(&s_mn[mk], o);                                           \
            atomicMax(&s_mx[mk], o);                                           \
            const int vf = __float2int_rn(mv * SCALEF);                        \
            atomicAdd(&s_sc[mk], (1ULL << CNT_SHIFT) +                         \
                      (unsigned long long)(unsigned)(vf + ELEM_BIAS));         \
        }

    const int stride = gridDim.x * BLK;
    int i = blockIdx.x * BLK + threadIdx.x;
    if (i < n4) {
        int4 k4 = keys[i]; float4 v4 = vals[i];
        for (i += stride; ; i += stride) {
            const bool more = (i < n4);
            int4 nk; float4 nv;
            if (more) { nk = keys[i]; nv = vals[i]; }   // 1-deep prefetch
            MAIN_ELEM(k4.x, v4.x) MAIN_ELEM(k4.y, v4.y)
            MAIN_ELEM(k4.z, v4.z) MAIN_ELEM(k4.w, v4.w)
            if (!more) break;
            k4 = nk; v4 = nv;
        }
    }
#undef MAIN_ELEM
    __syncthreads();

    // Fold: block cell n = cell>>42, s = (cell&mask) - n*2^24 (exact).
    // Global cell: n*2^44 + (s + n*2^23); per-element |vf| < 2^23 so the low
    // field stays non-negative and additive; totals << 2^44. Exact.
    const int r  = blockIdx.x & (NREP - 1);
    const int rm = blockIdx.x & (NREP_MM - 1);
    unsigned long long* __restrict__ racc_r  = racc  + (size_t)r  * G;
    unsigned*           __restrict__ rmaxo_r = rmaxo + (size_t)rm * G;
    unsigned*           __restrict__ rminv_r = rminv + (size_t)rm * G;
    for (int k = threadIdx.x; k < G; k += BLK) {
        const unsigned long long cell = s_sc[k];
        const unsigned n = (unsigned)(cell >> CNT_SHIFT);
        if (n) {
            const long long s = (long long)(cell & LOW_MASK) - ((long long)n << 24);
            atomicAdd(&racc_r[k],
                      ((unsigned long long)n << GCNT_SHIFT) +
                      (unsigned long long)(s + (long long)n * GSUM_BIAS));
            atomicMax(&rmaxo_r[k], s_mx[k]);
            atomicMax(&rminv_r[k], ~s_mn[k]);   // min inverted, identity 0
        }
    }

    // Last-block-done: make this block's global atomics visible, then elect.
    __threadfence();
    __shared__ unsigned s_last;
    if (threadIdx.x == 0) {
        const unsigned t = __hip_atomic_fetch_add(done, 1u, __ATOMIC_ACQ_REL,
                                                  __HIP_MEMORY_SCOPE_AGENT);
        s_last = (t == gridDim.x - 1) ? 1u : 0u;
    }
    __syncthreads();
    if (!s_last) return;

    // Final reduce + write (former gb_write), by the one last block.
    // Agent-scope atomic loads: safe across non-coherent per-XCD L2s.
    __threadfence();
    for (int k = threadIdx.x; k < G; k += BLK) {
        unsigned long long cell = 0ull;
        for (int q = 0; q < NREP; ++q)
            cell += __hip_atomic_load(&racc[(size_t)q * G + k],
                                      __ATOMIC_RELAXED, __HIP_MEMORY_SCOPE_AGENT);
        unsigned mx = 0u, mv = 0u;
        for (int q = 0; q < NREP_MM; ++q) {
            mx = max(mx, __hip_atomic_load(&rmaxo[(size_t)q * G + k],
                                           __ATOMIC_RELAXED, __HIP_MEMORY_SCOPE_AGENT));
            mv = max(mv, __hip_atomic_load(&rminv[(size_t)q * G + k],
                                           __ATOMIC_RELAXED, __HIP_MEMORY_SCOPE_AGENT));
        }
        const unsigned n = (unsigned)(cell >> GCNT_SHIFT);
        const long long s = (long long)(cell & GLOW_MASK) - (long long)n * GSUM_BIAS;
        const float sum = (float)((double)s * (1.0 / (double)SCALEF));
        const int g = (G - 1) - k;     // gid = 1023 - key
        out[g]         = (float)k;
        out[G + g]     = sum;
        out[2 * G + g] = sum / (float)n;
        out[3 * G + g] = ounmap(~mv);
        out[4 * G + g] = ounmap(mx);
    }
}

extern "C" void kernel_launch(void* const* d_in, const int* in_sizes, int n_in,
                              void* d_out, int out_size, void* d_ws, size_t ws_size,
                              hipStream_t stream) {
    const int4*   keys = (const int4*)d_in[0];
    const float4* vals = (const float4*)d_in[1];
    const int n  = in_sizes[0];
    const int n4 = n / 4;

    // Workspace: racc u64[64][G] (512KB) | rmaxo u32[32][G] | rminv u32[32][G] | done
    unsigned long long* racc  = (unsigned long long*)d_ws;
    unsigned*           rmaxo = (unsigned*)(racc + (size_t)NREP * G);
    unsigned*           rminv = rmaxo + (size_t)NREP_MM * G;
    unsigned*           done  = rminv + (size_t)NREP_MM * G;
    const size_t acc_bytes = (size_t)NREP * G * 8 + 2 * (size_t)NREP_MM * G * 4
                           + sizeof(unsigned);

    hipMemsetAsync(d_ws, 0, acc_bytes, stream);

    hipLaunchKernelGGL(gb_fused, dim3(GRID), dim3(BLK), 0, stream,
                       keys, vals, n4, racc, rmaxo, rminv, done, (float*)d_out);
}

// Round 8
// 158.772 us; speedup vs baseline: 2.1651x; 2.1651x over previous
//
#include <hip/hip_runtime.h>

#define G 1024
#define SCALEF 1048576.0f         // 2^20 fixed-point for the sum (exact decode, absmax ~4e-6)
#define CNT_SHIFT 42              // block cell (u64): count [42..63], biased sum [0..41]
#define ELEM_BIAS (1 << 24)       // per-element bias (> max |vf|, |v| < 16)
#define LOW_MASK ((1ULL << CNT_SHIFT) - 1)
#define GCNT_SHIFT 44             // global cell (u64): count [44..63], biased sum below
#define GSUM_BIAS (1ll << 23)     // per-count bias (>= max per-element |vf|, |v| < 8)
#define GLOW_MASK ((1ULL << GCNT_SHIFT) - 1)
#define NREP 32                   // sum-fold replicas: 1024 blocks / 32 -> depth 32 per address
#define NREP_MM 16                // min/max replicas
#define BLK 512
#define GRID 1024

// Order-preserving map float -> uint32 (monotone): uint min/max == float min/max.
__device__ __forceinline__ unsigned omap(float x) {
    unsigned u = __float_as_uint(x);
    return (u & 0x80000000u) ? ~u : (u | 0x80000000u);
}
__device__ __forceinline__ float ounmap(unsigned o) {
    unsigned u = (o & 0x80000000u) ? (o & 0x7fffffffu) : ~o;
    return __uint_as_float(u);
}

// Single fused kernel (R8): main pass + last-block-done final reduce/write,
// WITHOUT __threadfence. R7 lesson: __threadfence() (per-wave L2 wb/inv on
// non-coherent XCD L2s) cost +230us. It is unnecessary: all workspace writes
// are device-scope atomics (complete at the coherence point), __syncthreads
// drains vmcnt(0) per wave (the LLVM agent-release mechanism for
// cache-bypassing ops), and the last block reads back with relaxed
// agent-scope ATOMIC loads (bypass the stale caches by construction).
__global__ __launch_bounds__(BLK) void gb_fused(
    const int4* __restrict__ keys, const float4* __restrict__ vals, int n4,
    unsigned long long* __restrict__ racc,
    unsigned* __restrict__ rmaxo, unsigned* __restrict__ rminv,
    unsigned* __restrict__ done, float* __restrict__ out)
{
    __shared__ unsigned long long s_sc[G];
    __shared__ unsigned s_mn[G];
    __shared__ unsigned s_mx[G];
    for (int k = threadIdx.x; k < G; k += BLK) {
        s_sc[k] = 0ull; s_mn[k] = 0xffffffffu; s_mx[k] = 0u;
    }
    __syncthreads();

#define MAIN_ELEM(KK, VV)                                                      \
        {                                                                      \
            const int mk = (KK); const float mv = (VV);                        \
            const unsigned o = omap(mv);                                       \
            atomicMin(&s_mn[mk], o);                                           \
            atomicMax(&s_mx[mk], o);                                           \
            const int vf = __float2int_rn(mv * SCALEF);                        \
            atomicAdd(&s_sc[mk], (1ULL << CNT_SHIFT) +                         \
                      (unsigned long long)(unsigned)(vf + ELEM_BIAS));         \
        }

    const int stride = gridDim.x * BLK;
    int i = blockIdx.x * BLK + threadIdx.x;
    if (i < n4) {
        int4 k4 = keys[i]; float4 v4 = vals[i];
        for (i += stride; ; i += stride) {
            const bool more = (i < n4);
            int4 nk; float4 nv;
            if (more) { nk = keys[i]; nv = vals[i]; }   // 1-deep prefetch
            MAIN_ELEM(k4.x, v4.x) MAIN_ELEM(k4.y, v4.y)
            MAIN_ELEM(k4.z, v4.z) MAIN_ELEM(k4.w, v4.w)
            if (!more) break;
            k4 = nk; v4 = nv;
        }
    }
#undef MAIN_ELEM
    __syncthreads();

    // Fold: block cell n = cell>>42, s = (cell&mask) - n*2^24 (exact).
    // Global cell: n*2^44 + (s + n*2^23); per-element |vf| < 2^23 so the low
    // field stays non-negative and additive; totals << 2^44. Exact.
    const int r  = blockIdx.x & (NREP - 1);
    const int rm = blockIdx.x & (NREP_MM - 1);
    unsigned long long* __restrict__ racc_r  = racc  + (size_t)r  * G;
    unsigned*           __restrict__ rmaxo_r = rmaxo + (size_t)rm * G;
    unsigned*           __restrict__ rminv_r = rminv + (size_t)rm * G;
    for (int k = threadIdx.x; k < G; k += BLK) {
        const unsigned long long cell = s_sc[k];
        const unsigned n = (unsigned)(cell >> CNT_SHIFT);
        if (n) {
            const long long s = (long long)(cell & LOW_MASK) - ((long long)n << 24);
            atomicAdd(&racc_r[k],
                      ((unsigned long long)n << GCNT_SHIFT) +
                      (unsigned long long)(s + (long long)n * GSUM_BIAS));
            atomicMax(&rmaxo_r[k], s_mx[k]);
            atomicMax(&rminv_r[k], ~s_mn[k]);   // min inverted, identity 0
        }
    }

    // Last-block election. __syncthreads() drains each wave's vmcnt(0) before
    // the barrier -> all this block's device-scope atomics have completed at
    // the coherence point before thread 0 increments `done`. No cache flush.
    __syncthreads();
    __shared__ unsigned s_last;
    if (threadIdx.x == 0) {
        const unsigned t = __hip_atomic_fetch_add(done, 1u, __ATOMIC_RELAXED,
                                                  __HIP_MEMORY_SCOPE_AGENT);
        s_last = (t == gridDim.x - 1) ? 1u : 0u;
    }
    __syncthreads();
    if (!s_last) return;

    // Final reduce + write, by the one last block. Relaxed agent-scope atomic
    // loads: execute at the coherence point, immune to stale per-XCD L2s.
    for (int k = threadIdx.x; k < G; k += BLK) {
        unsigned long long cell = 0ull;
#pragma unroll
        for (int q = 0; q < NREP; ++q)
            cell += __hip_atomic_load(&racc[(size_t)q * G + k],
                                      __ATOMIC_RELAXED, __HIP_MEMORY_SCOPE_AGENT);
        unsigned mx = 0u, mv = 0u;
#pragma unroll
        for (int q = 0; q < NREP_MM; ++q) {
            mx = max(mx, __hip_atomic_load(&rmaxo[(size_t)q * G + k],
                                           __ATOMIC_RELAXED, __HIP_MEMORY_SCOPE_AGENT));
            mv = max(mv, __hip_atomic_load(&rminv[(size_t)q * G + k],
                                           __ATOMIC_RELAXED, __HIP_MEMORY_SCOPE_AGENT));
        }
        const unsigned n = (unsigned)(cell >> GCNT_SHIFT);
        const long long s = (long long)(cell & GLOW_MASK) - (long long)n * GSUM_BIAS;
        const float sum = (float)((double)s * (1.0 / (double)SCALEF));
        const int g = (G - 1) - k;     // gid = 1023 - key
        out[g]         = (float)k;
        out[G + g]     = sum;
        out[2 * G + g] = sum / (float)n;
        out[3 * G + g] = ounmap(~mv);
        out[4 * G + g] = ounmap(mx);
    }
}

extern "C" void kernel_launch(void* const* d_in, const int* in_sizes, int n_in,
                              void* d_out, int out_size, void* d_ws, size_t ws_size,
                              hipStream_t stream) {
    const int4*   keys = (const int4*)d_in[0];
    const float4* vals = (const float4*)d_in[1];
    const int n  = in_sizes[0];
    const int n4 = n / 4;

    // Workspace: racc u64[32][G] (256KB) | rmaxo u32[16][G] | rminv u32[16][G] | done
    unsigned long long* racc  = (unsigned long long*)d_ws;
    unsigned*           rmaxo = (unsigned*)(racc + (size_t)NREP * G);
    unsigned*           rminv = rmaxo + (size_t)NREP_MM * G;
    unsigned*           done  = rminv + (size_t)NREP_MM * G;
    const size_t acc_bytes = (size_t)NREP * G * 8 + 2 * (size_t)NREP_MM * G * 4
                           + sizeof(unsigned);

    hipMemsetAsync(d_ws, 0, acc_bytes, stream);

    hipLaunchKernelGGL(gb_fused, dim3(GRID), dim3(BLK), 0, stream,
                       keys, vals, n4, racc, rmaxo, rminv, done, (float*)d_out);
}